// Round 2
// baseline (1171.128 us; speedup 1.0000x reference)
//
#include <hip/hip_runtime.h>

#define BATCH 16

// ---------------- d-step (levels 1-3): 4-lane groups, lane j owns vec[j] ----
// unit = (p, b); 4 lanes per unit. total threads = nh*nh*16*4 (multiple of 64)
__global__ __launch_bounds__(256) void d_kernel_j(
    float* __restrict__ h, const float* __restrict__ A,
    const float* __restrict__ v, const float* __restrict__ w,
    int H, int nh) {
  int g = blockIdx.x * blockDim.x + threadIdx.x;
  int total = nh * nh * BATCH * 4;
  if (g >= total) return;  // whole waves exit together (total % 64 == 0)
  int j = g & 3;
  int b = (g >> 2) & 15;
  int p = g >> 6;
  int pi = p / nh, pj = p % nh;
  float* xb = h + (size_t)b * H * H;
  int r0 = 1 + 2 * pi, c0 = 1 + 2 * pj;
  float t[4];
  t[0] = xb[r0 * H + c0];
  t[1] = xb[r0 * H + c0 + 1];
  t[2] = xb[(r0 + 1) * H + c0];
  t[3] = xb[(r0 + 1) * H + c0 + 1];
  const float* Ap = A + (size_t)p * 128;  // [s][f][4][4]
  float vec = v[p * 4 + j];
#pragma unroll
  for (int s = 0; s < 4; s++) {
    float ts = t[s], us = 1.0f - ts;
    const float* A0 = Ap + s * 32;
    const float* A1 = A0 + 16;
    float vn = 0.0f;
#pragma unroll
    for (int i = 0; i < 4; i++) {
      float m = ts * A0[i * 4 + j] + us * A1[i * 4 + j];
      vn += __shfl(vec, i, 4) * m;
    }
    vec = vn;
  }
  // y_j = relu(sum_i vec_i * w[i*4+j])
  float acc = 0.0f;
#pragma unroll
  for (int i = 0; i < 4; i++) acc += __shfl(vec, i, 4) * w[p * 16 + i * 4 + j];
  acc = fmaxf(acc, 0.0f);
  int r = r0 + (j >> 1), c = c0 + (j & 1);
  xb[r * H + c] = acc;
}

// ---------------- i-step (levels 1-3): 16-lane groups ------------------------
// unit = (p, b); 16 lanes per unit. grid: one block (256 thr) per patch.
__global__ __launch_bounds__(256) void i_kernel_j(
    const float* __restrict__ h, float* __restrict__ hn,
    const float* __restrict__ A, const float* __restrict__ v,
    const float* __restrict__ w, int H) {
  int W2 = H >> 1;
  int g = blockIdx.x * blockDim.x + threadIdx.x;
  int j = g & 15;
  int b = (g >> 4) & 15;
  int p = g >> 8;
  int pi = p / W2, pj = p % W2;
  const float* xb = h + (size_t)b * H * H;
  int r0 = 2 * pi, c0 = 2 * pj;
  float t[4];
  t[0] = xb[r0 * H + c0];
  t[1] = xb[r0 * H + c0 + 1];
  t[2] = xb[(r0 + 1) * H + c0];
  t[3] = xb[(r0 + 1) * H + c0 + 1];
  const float* Ap = A + (size_t)p * 2048;  // [s][f][16][16]
  float vec = v[p * 16 + j];
#pragma unroll
  for (int s = 0; s < 4; s++) {
    float ts = t[s], us = 1.0f - ts;
    const float* A0 = Ap + s * 512;
    const float* A1 = A0 + 256;
    float vn = 0.0f;
#pragma unroll
    for (int i = 0; i < 16; i++) {
      float m = ts * A0[i * 16 + j] + us * A1[i * 16 + j];
      vn += __shfl(vec, i, 16) * m;
    }
    vec = vn;
  }
  float partial = vec * w[p * 16 + j];
#pragma unroll
  for (int off = 8; off >= 1; off >>= 1)
    partial += __shfl_xor(partial, off, 16);
  if (j == 0) hn[(size_t)b * W2 * W2 + p] = fmaxf(partial, 0.0f);
}

// ---------------- fused tail: levels 4-6 + final head, one block -------------
__device__ __forceinline__ void d_step_local(float* xl, const float* A,
                                             const float* v, const float* w,
                                             int H, int nh, int tid) {
  int n = nh * nh * BATCH;
  if (tid < n) {
    int b = tid & 15;
    int p = tid >> 4;
    int pi = p / nh, pj = p % nh;
    float* xb = xl + b * H * H;
    int r0 = 1 + 2 * pi, c0 = 1 + 2 * pj;
    float t[4];
    t[0] = xb[r0 * H + c0];
    t[1] = xb[r0 * H + c0 + 1];
    t[2] = xb[(r0 + 1) * H + c0];
    t[3] = xb[(r0 + 1) * H + c0 + 1];
    const float* Ap = A + (size_t)p * 128;
    float vec[4];
#pragma unroll
    for (int i = 0; i < 4; i++) vec[i] = v[p * 4 + i];
#pragma unroll
    for (int s = 0; s < 4; s++) {
      float ts = t[s], us = 1.0f - ts;
      const float* A0 = Ap + s * 32;
      const float* A1 = A0 + 16;
      float vn[4] = {0.f, 0.f, 0.f, 0.f};
#pragma unroll
      for (int i = 0; i < 4; i++) {
        float vi = vec[i];
#pragma unroll
        for (int q = 0; q < 4; q++)
          vn[q] += vi * (ts * A0[i * 4 + q] + us * A1[i * 4 + q]);
      }
#pragma unroll
      for (int q = 0; q < 4; q++) vec[q] = vn[q];
    }
    const float* wp = w + p * 16;
    float y[4];
#pragma unroll
    for (int o = 0; o < 4; o++) {
      float acc = 0.f;
#pragma unroll
      for (int i = 0; i < 4; i++) acc += vec[i] * wp[i * 4 + o];
      y[o] = fmaxf(acc, 0.0f);
    }
    xb[r0 * H + c0] = y[0];
    xb[r0 * H + c0 + 1] = y[1];
    xb[(r0 + 1) * H + c0] = y[2];
    xb[(r0 + 1) * H + c0 + 1] = y[3];
  }
  __syncthreads();
}

__device__ __forceinline__ void i_step_local(const float* xl, float* hl,
                                             const float* A, const float* v,
                                             const float* w, int H, int tid) {
  int W2 = H >> 1;
  int n = W2 * W2 * BATCH;
  if (tid < n) {
    int b = tid & 15;
    int p = tid >> 4;
    int pi = p / W2, pj = p % W2;
    const float* xb = xl + b * H * H;
    int r0 = 2 * pi, c0 = 2 * pj;
    float t[4];
    t[0] = xb[r0 * H + c0];
    t[1] = xb[r0 * H + c0 + 1];
    t[2] = xb[(r0 + 1) * H + c0];
    t[3] = xb[(r0 + 1) * H + c0 + 1];
    const float* Ap = A + (size_t)p * 2048;
    float vec[16];
#pragma unroll
    for (int i = 0; i < 16; i++) vec[i] = v[p * 16 + i];
#pragma unroll
    for (int s = 0; s < 4; s++) {
      float ts = t[s], us = 1.0f - ts;
      const float4* A0 = (const float4*)(Ap + s * 512);
      const float4* A1 = (const float4*)(Ap + s * 512 + 256);
      float vn[16];
#pragma unroll
      for (int q = 0; q < 16; q++) vn[q] = 0.0f;
#pragma unroll
      for (int i = 0; i < 16; i++) {
        float vi = vec[i];
#pragma unroll
        for (int q = 0; q < 4; q++) {
          float4 a0 = A0[i * 4 + q];
          float4 a1 = A1[i * 4 + q];
          vn[q * 4 + 0] += vi * (ts * a0.x + us * a1.x);
          vn[q * 4 + 1] += vi * (ts * a0.y + us * a1.y);
          vn[q * 4 + 2] += vi * (ts * a0.z + us * a1.z);
          vn[q * 4 + 3] += vi * (ts * a0.w + us * a1.w);
        }
      }
#pragma unroll
      for (int q = 0; q < 16; q++) vec[q] = vn[q];
    }
    float acc = 0.f;
#pragma unroll
    for (int i = 0; i < 16; i++) acc += vec[i] * w[p * 16 + i];
    hl[b * W2 * W2 + p] = fmaxf(acc, 0.0f);
  }
  __syncthreads();
}

__global__ __launch_bounds__(1024) void tail_kernel(
    const float* __restrict__ h3,
    const float* __restrict__ d4A, const float* __restrict__ d4v, const float* __restrict__ d4w,
    const float* __restrict__ i4A, const float* __restrict__ i4v, const float* __restrict__ i4w,
    const float* __restrict__ d5A, const float* __restrict__ d5v, const float* __restrict__ d5w,
    const float* __restrict__ i5A, const float* __restrict__ i5v, const float* __restrict__ i5w,
    const float* __restrict__ d6A, const float* __restrict__ d6v, const float* __restrict__ d6w,
    const float* __restrict__ i6A, const float* __restrict__ i6v, const float* __restrict__ i6w,
    const float* __restrict__ fA, const float* __restrict__ fv, const float* __restrict__ fw,
    float* __restrict__ out) {
  __shared__ float x4[16 * 16 * 16];  // level-4 input, H=16
  __shared__ float h4[16 * 8 * 8];    // level-5 input, H=8
  __shared__ float h5[16 * 4 * 4];    // level-6 input, H=4
  __shared__ float h6[16 * 2 * 2];
  int tid = threadIdx.x;
  for (int k = tid; k < 4096; k += 1024) x4[k] = h3[k];
  __syncthreads();

  d_step_local(x4, d4A, d4v, d4w, 16, 7, tid);
  i_step_local(x4, h4, i4A, i4v, i4w, 16, tid);
  d_step_local(h4, d5A, d5v, d5w, 8, 3, tid);
  i_step_local(h4, h5, i5A, i5v, i5w, 8, tid);
  d_step_local(h5, d6A, d6v, d6w, 4, 1, tid);
  i_step_local(h5, h6, i6A, i6v, i6w, 4, tid);

  // final head: 16 threads (one per batch element)
  if (tid < BATCH) {
    int b = tid;
    float t[4];
#pragma unroll
    for (int s = 0; s < 4; s++) t[s] = h6[b * 4 + s];
    float vec[16];
#pragma unroll
    for (int i = 0; i < 16; i++) vec[i] = fv[i];
#pragma unroll
    for (int s = 0; s < 4; s++) {
      float ts = t[s], us = 1.0f - ts;
      const float* A0 = fA + s * 512;
      const float* A1 = A0 + 256;
      float vn[16];
#pragma unroll
      for (int q = 0; q < 16; q++) vn[q] = 0.0f;
#pragma unroll
      for (int i = 0; i < 16; i++) {
        float vi = vec[i];
#pragma unroll
        for (int q = 0; q < 16; q++)
          vn[q] += vi * (ts * A0[i * 16 + q] + us * A1[i * 16 + q]);
      }
#pragma unroll
      for (int q = 0; q < 16; q++) vec[q] = vn[q];
    }
#pragma unroll
    for (int o = 0; o < 10; o++) {
      float acc = 0.f;
#pragma unroll
      for (int i = 0; i < 16; i++) acc += vec[i] * fw[i * 10 + o];
      out[b * 10 + o] = fmaxf(acc, 0.0f);
    }
  }
}

extern "C" void kernel_launch(void* const* d_in, const int* in_sizes, int n_in,
                              void* d_out, int out_size, void* d_ws, size_t ws_size,
                              hipStream_t stream) {
  const float* x = (const float*)d_in[0];
  float* ws = (float*)d_ws;

  hipMemcpyAsync(ws, x, (size_t)BATCH * 128 * 128 * sizeof(float),
                 hipMemcpyDeviceToDevice, stream);

  int H = 128;
  size_t hoff = 0;
  for (int l = 0; l < 3; l++) {
    const float* dA = (const float*)d_in[1 + 6 * l + 0];
    const float* dv = (const float*)d_in[1 + 6 * l + 1];
    const float* dw = (const float*)d_in[1 + 6 * l + 2];
    const float* iA = (const float*)d_in[1 + 6 * l + 3];
    const float* iv = (const float*)d_in[1 + 6 * l + 4];
    const float* iw = (const float*)d_in[1 + 6 * l + 5];

    int nh = (H - 2) / 2;
    int totd = nh * nh * BATCH * 4;
    d_kernel_j<<<(totd + 255) / 256, 256, 0, stream>>>(ws + hoff, dA, dv, dw, H, nh);

    int W2 = H / 2;
    size_t hoff_next = hoff + (size_t)BATCH * H * H;
    int toti = W2 * W2 * BATCH * 16;  // multiple of 256
    i_kernel_j<<<toti / 256, 256, 0, stream>>>(ws + hoff, ws + hoff_next,
                                               iA, iv, iw, H);
    hoff = hoff_next;
    H = W2;
  }

  tail_kernel<<<1, 1024, 0, stream>>>(
      ws + hoff,
      (const float*)d_in[19], (const float*)d_in[20], (const float*)d_in[21],
      (const float*)d_in[22], (const float*)d_in[23], (const float*)d_in[24],
      (const float*)d_in[25], (const float*)d_in[26], (const float*)d_in[27],
      (const float*)d_in[28], (const float*)d_in[29], (const float*)d_in[30],
      (const float*)d_in[31], (const float*)d_in[32], (const float*)d_in[33],
      (const float*)d_in[34], (const float*)d_in[35], (const float*)d_in[36],
      (const float*)d_in[37], (const float*)d_in[38], (const float*)d_in[39],
      (float*)d_out);
}

// Round 3
// 230.190 us; speedup vs baseline: 5.0876x; 5.0876x over previous
//
#include <hip/hip_runtime.h>

#define BATCH 16

// ---------------- d-step: 4-lane groups, lane j owns vec[j] ------------------
// unit = (p, b); 4 lanes per unit. total threads = nh*nh*16*4
__global__ __launch_bounds__(256) void d_kernel_j(
    float* __restrict__ h, const float* __restrict__ A,
    const float* __restrict__ v, const float* __restrict__ w,
    int H, int nh) {
  int g = blockIdx.x * blockDim.x + threadIdx.x;
  int total = nh * nh * BATCH * 4;
  if (g >= total) return;
  int j = g & 3;
  int b = (g >> 2) & 15;
  int p = g >> 6;
  int pi = p / nh, pj = p % nh;
  float* xb = h + (size_t)b * H * H;
  int r0 = 1 + 2 * pi, c0 = 1 + 2 * pj;
  float t[4];
  t[0] = xb[r0 * H + c0];
  t[1] = xb[r0 * H + c0 + 1];
  t[2] = xb[(r0 + 1) * H + c0];
  t[3] = xb[(r0 + 1) * H + c0 + 1];
  const float* Ap = A + (size_t)p * 128;  // [s][f][4][4]
  float vec = v[p * 4 + j];
#pragma unroll
  for (int s = 0; s < 4; s++) {
    float ts = t[s], us = 1.0f - ts;
    const float* A0 = Ap + s * 32;
    const float* A1 = A0 + 16;
    float vn = 0.0f;
#pragma unroll
    for (int i = 0; i < 4; i++) {
      float m = ts * A0[i * 4 + j] + us * A1[i * 4 + j];
      vn += __shfl(vec, i, 4) * m;
    }
    vec = vn;
  }
  float acc = 0.0f;
#pragma unroll
  for (int i = 0; i < 4; i++) acc += __shfl(vec, i, 4) * w[p * 16 + i * 4 + j];
  acc = fmaxf(acc, 0.0f);
  int r = r0 + (j >> 1), c = c0 + (j & 1);
  xb[r * H + c] = acc;
}

// ---------------- i-step: 16-lane groups, lane j owns vec[j] -----------------
// unit = (p, b); 16 lanes per unit.
__global__ __launch_bounds__(256) void i_kernel_j(
    const float* __restrict__ h, float* __restrict__ hn,
    const float* __restrict__ A, const float* __restrict__ v,
    const float* __restrict__ w, int H) {
  int W2 = H >> 1;
  int g = blockIdx.x * blockDim.x + threadIdx.x;
  int j = g & 15;
  int b = (g >> 4) & 15;
  int p = g >> 8;
  int pi = p / W2, pj = p % W2;
  const float* xb = h + (size_t)b * H * H;
  int r0 = 2 * pi, c0 = 2 * pj;
  float t[4];
  t[0] = xb[r0 * H + c0];
  t[1] = xb[r0 * H + c0 + 1];
  t[2] = xb[(r0 + 1) * H + c0];
  t[3] = xb[(r0 + 1) * H + c0 + 1];
  const float* Ap = A + (size_t)p * 2048;  // [s][f][16][16]
  float vec = v[p * 16 + j];
#pragma unroll
  for (int s = 0; s < 4; s++) {
    float ts = t[s], us = 1.0f - ts;
    const float* A0 = Ap + s * 512;
    const float* A1 = A0 + 256;
    float vn = 0.0f;
#pragma unroll
    for (int i = 0; i < 16; i++) {
      float m = ts * A0[i * 16 + j] + us * A1[i * 16 + j];
      vn += __shfl(vec, i, 16) * m;
    }
    vec = vn;
  }
  float partial = vec * w[p * 16 + j];
#pragma unroll
  for (int off = 8; off >= 1; off >>= 1)
    partial += __shfl_xor(partial, off, 16);
  if (j == 0) hn[(size_t)b * W2 * W2 + p] = fmaxf(partial, 0.0f);
}

// ---------------- final head: (16,2,2) -> (16,10) ----------------------------
__global__ void final_kernel(const float* __restrict__ h6,
                             const float* __restrict__ A,
                             const float* __restrict__ v,
                             const float* __restrict__ w,
                             float* __restrict__ out) {
  int b = threadIdx.x;
  if (b >= BATCH) return;
  float t[4];
#pragma unroll
  for (int s = 0; s < 4; s++) t[s] = h6[b * 4 + s];
  float vec[16];
#pragma unroll
  for (int i = 0; i < 16; i++) vec[i] = v[i];
#pragma unroll
  for (int s = 0; s < 4; s++) {
    float ts = t[s], us = 1.0f - ts;
    const float* A0 = A + s * 512;
    const float* A1 = A0 + 256;
    float vn[16];
#pragma unroll
    for (int q = 0; q < 16; q++) vn[q] = 0.0f;
#pragma unroll
    for (int i = 0; i < 16; i++) {
      float vi = vec[i];
#pragma unroll
      for (int q = 0; q < 16; q++)
        vn[q] += vi * (ts * A0[i * 16 + q] + us * A1[i * 16 + q]);
    }
#pragma unroll
    for (int q = 0; q < 16; q++) vec[q] = vn[q];
  }
#pragma unroll
  for (int o = 0; o < 10; o++) {
    float acc = 0.f;
#pragma unroll
    for (int i = 0; i < 16; i++) acc += vec[i] * w[i * 10 + o];
    out[b * 10 + o] = fmaxf(acc, 0.0f);
  }
}

extern "C" void kernel_launch(void* const* d_in, const int* in_sizes, int n_in,
                              void* d_out, int out_size, void* d_ws, size_t ws_size,
                              hipStream_t stream) {
  const float* x = (const float*)d_in[0];
  float* ws = (float*)d_ws;

  // seed h-pyramid level 0
  hipMemcpyAsync(ws, x, (size_t)BATCH * 128 * 128 * sizeof(float),
                 hipMemcpyDeviceToDevice, stream);

  int H = 128;
  size_t hoff = 0;
  for (int l = 0; l < 6; l++) {
    const float* dA = (const float*)d_in[1 + 6 * l + 0];
    const float* dv = (const float*)d_in[1 + 6 * l + 1];
    const float* dw = (const float*)d_in[1 + 6 * l + 2];
    const float* iA = (const float*)d_in[1 + 6 * l + 3];
    const float* iv = (const float*)d_in[1 + 6 * l + 4];
    const float* iw = (const float*)d_in[1 + 6 * l + 5];

    int nh = (H - 2) / 2;
    int totd = nh * nh * BATCH * 4;
    d_kernel_j<<<(totd + 255) / 256, 256, 0, stream>>>(ws + hoff, dA, dv, dw, H, nh);

    int W2 = H / 2;
    size_t hoff_next = hoff + (size_t)BATCH * H * H;
    int toti = W2 * W2 * BATCH * 16;  // always a multiple of 256
    i_kernel_j<<<toti / 256, 256, 0, stream>>>(ws + hoff, ws + hoff_next,
                                               iA, iv, iw, H);
    hoff = hoff_next;
    H = W2;
  }

  final_kernel<<<1, 64, 0, stream>>>(ws + hoff, (const float*)d_in[37],
                                     (const float*)d_in[38],
                                     (const float*)d_in[39], (float*)d_out);
}